// Round 12
// baseline (236.151 us; speedup 1.0000x reference)
//
#include <hip/hip_runtime.h>

#define D 128
#define TN 64      // nodes per block
#define NR 3       // relations

typedef short short8 __attribute__((ext_vector_type(8)));
typedef float f32x4 __attribute__((ext_vector_type(4)));

// round-to-nearest-even f32 -> bf16 bits
__device__ __forceinline__ unsigned int f2bf(float x) {
    unsigned int u = __float_as_uint(x);
    return (u + 0x7fffu + ((u >> 16) & 1u)) >> 16;
}

// f32 -> fp8 e4m3fn bits (RNE, clamp to ±448, denormal-correct)
__device__ __forceinline__ unsigned int f2fp8(float x) {
    unsigned int u = __float_as_uint(x);
    unsigned int s = (u >> 24) & 0x80u;
    unsigned int t = u & 0x7fffffffu;
    if (t >= 0x43E00000u) return s | 0x7Eu;      // >= 448 -> clamp to max
    if (t < 0x3C800000u) {                       // |x| < 2^-6 -> fp8 denormal
        unsigned int m = (unsigned int)rintf(fabsf(x) * 512.0f);  // 0..8
        return s | m;                            // m==8 == 2^-6 normal, OK
    }
    unsigned int r = t + 0x7FFFFu + ((t >> 20) & 1u);   // RNE at bit 20
    unsigned int b = (r >> 20) - 960u;                  // rebias (127-7)<<3
    if (b > 0x7Eu) b = 0x7Eu;
    return s | b;
}

// fp8 e4m3fn byte -> f32 (exact for normals; f32-denormal path may flush ->
// loses |x|<2^-6 values, error <= 0.016 on ~1.2% of elements: negligible)
__device__ __forceinline__ float fp8f(unsigned int b) {
    unsigned int t = ((b & 0x80u) << 24) | ((b & 0x7Fu) << 20);
    return __uint_as_float(t) * 0x1p120f;
}

// ---------------- prep: h -> {bf16 hb, fp8 h8} (+zero sink rows) AND W pack --
__global__ __launch_bounds__(256) void prep_k(const float* __restrict__ h,
                                              unsigned short* __restrict__ hb,
                                              unsigned char* __restrict__ h8,
                                              const float* __restrict__ W,
                                              unsigned short* __restrict__ Wb,
                                              int n8, int n8tot, int nbConv) {
    if ((int)blockIdx.x < nbConv) {
        int i = blockIdx.x * 256 + threadIdx.x;
        if (i >= n8tot) return;
        if (i >= n8) {  // zero sink row
            ((uint4*)hb)[i] = make_uint4(0u, 0u, 0u, 0u);
            ((uint2*)h8)[i] = make_uint2(0u, 0u);
            return;
        }
        const float4* hp = (const float4*)h;
        float4 v0 = hp[2 * i + 0], v1 = hp[2 * i + 1];
        uint4 o;
        o.x = f2bf(v0.x) | (f2bf(v0.y) << 16);
        o.y = f2bf(v0.z) | (f2bf(v0.w) << 16);
        o.z = f2bf(v1.x) | (f2bf(v1.y) << 16);
        o.w = f2bf(v1.z) | (f2bf(v1.w) << 16);
        ((uint4*)hb)[i] = o;
        unsigned int w0 = f2fp8(v0.x) | (f2fp8(v0.y) << 8) |
                          (f2fp8(v0.z) << 16) | (f2fp8(v0.w) << 24);
        unsigned int w1 = f2fp8(v1.x) | (f2fp8(v1.y) << 8) |
                          (f2fp8(v1.z) << 16) | (f2fp8(v1.w) << 24);
        ((uint2*)h8)[i] = make_uint2(w0, w1);
    } else {
        int t = ((int)blockIdx.x - nbConv) * 256 + threadIdx.x;
        if (t >= 12 * 8 * 64) return;
        int lane = t & 63, cg = (t >> 6) & 7, kg = t >> 9;
        int col = cg * 16 + (lane & 15);
        int r = kg >> 2;
        int klocal = (kg & 3) * 32 + (lane >> 4) * 8;
        const float* Ws = W + ((size_t)r * D + klocal) * D + col;
        uint4 o;
        o.x = f2bf(Ws[0 * D]) | (f2bf(Ws[1 * D]) << 16);
        o.y = f2bf(Ws[2 * D]) | (f2bf(Ws[3 * D]) << 16);
        o.z = f2bf(Ws[4 * D]) | (f2bf(Ws[5 * D]) << 16);
        o.w = f2bf(Ws[6 * D]) | (f2bf(Ws[7 * D]) << 16);
        ((uint4*)Wb)[t] = o;
    }
}

// ---------------- chain build: one pass, coalesced 8B writes -----------------
__global__ void chain_k(const int* __restrict__ src, const int* __restrict__ dst,
                        int* __restrict__ head, int2* __restrict__ chain,
                        int E, int N, int nbE) {
    int r = blockIdx.x / nbE;
    int i = (blockIdx.x - r * nbE) * 256 + threadIdx.x;
    if (i >= E) return;
    size_t gi = (size_t)r * E + i;
    int d = dst[gi];
    int s = src[gi];
    int old = atomicExch(&head[r * N + d], (int)gi);
    chain[gi] = make_int2(s, old);
}

// ---------------- fused: walk -> 2x(fp8 gather half -> MFMA half) -> epilogue
// Block = 512 threads, 64 output rows, K = 384 (3 rel x 128 feat).
// LDS: Ald 24 KB + idxs 12 KB + degs/ovfs 1.5 KB -> 4 blocks/CU.
// Gather reads fp8 rows: one 64B line per (node,rel,half) instead of two.
__global__ __launch_bounds__(512, 8) void fused_k(
    const unsigned char* __restrict__ h8, const unsigned short* __restrict__ hb,
    const int* __restrict__ head, const int2* __restrict__ chain,
    const unsigned short* __restrict__ Wb, float* __restrict__ out, int N) {
    __shared__ uint4 Ald[4 * 6 * 64];       // 24 KB
    __shared__ int idxs[NR][16][TN];        // 12 KB
    __shared__ int degs[NR][TN];
    __shared__ int ovfs[NR][TN];

    const int tid = threadIdx.x;
    const int blk = blockIdx.x;

    // ---- phase W: walk chains into LDS (192 walkers) ----
    if (tid < NR * TN) {
        int r = tid / TN, nl = tid - r * TN;
        int n = blk * TN + nl;
        if (n >= N) n = N - 1;
        int e = head[r * N + n];
        int d = 0, ov = -1;
        while (e >= 0) {
            if (d == 16) ov = e;            // 17th edge onward: overflow walk
            int2 ce = chain[e];
            if (d < 16) idxs[r][d][nl] = ce.x;
            ++d;
            e = ce.y;
        }
        degs[r][nl] = d;
        ovfs[r][nl] = ov;
    }
    __syncthreads();

    const int lane = tid & 63;
    const int kgl = (tid >> 6) & 1;             // k sub-block within half
    const int rg = tid >> 7;                    // rowgrp 0..3
    const int nl = rg * 16 + (lane & 15);       // local node 0..63
    const int w = tid >> 6;                     // wave 0..7
    const int wr = w >> 2, wc = w & 3;          // 2 x 4 wave grid for MFMA

    const short8* Ap = (const short8*)Ald;
    const short8* Bp = (const short8*)Wb;
    f32x4 acc[2][2];
#pragma unroll
    for (int m = 0; m < 2; ++m)
#pragma unroll
        for (int n = 0; n < 2; ++n) acc[m][n] = (f32x4){0.f, 0.f, 0.f, 0.f};

    int cnt[NR];
#pragma unroll
    for (int r = 0; r < NR; ++r) cnt[r] = degs[r][nl];

#define ACCF8(v)                                                             \
    {                                                                        \
        unsigned int w0 = (v).x, w1 = (v).y;                                 \
        a0 += fp8f(w0 & 0xffu);                                              \
        a1 += fp8f((w0 >> 8) & 0xffu);                                       \
        a2 += fp8f((w0 >> 16) & 0xffu);                                      \
        a3 += fp8f(w0 >> 24);                                                \
        a4 += fp8f(w1 & 0xffu);                                              \
        a5 += fp8f((w1 >> 8) & 0xffu);                                       \
        a6 += fp8f((w1 >> 16) & 0xffu);                                      \
        a7 += fp8f(w1 >> 24);                                                \
    }
#define GLD8(s) (*(const uint2*)(h8 + ((size_t)(s) << 7) + c))

#pragma unroll
    for (int khalf = 0; khalf < 2; ++khalf) {
        const int c = khalf * 64 + kgl * 32 + ((lane >> 4) << 3);
        for (int r = 0; r < NR; ++r) {
            int cr = cnt[r];
            float a0 = 0, a1 = 0, a2 = 0, a3 = 0, a4 = 0, a5 = 0, a6 = 0,
                  a7 = 0;
            {   // first 8, branchless sink-padded (8 x 8B loads in flight)
                int s0 = (0 < cr) ? idxs[r][0][nl] : N;
                int s1 = (1 < cr) ? idxs[r][1][nl] : N;
                int s2 = (2 < cr) ? idxs[r][2][nl] : N;
                int s3 = (3 < cr) ? idxs[r][3][nl] : N;
                int s4 = (4 < cr) ? idxs[r][4][nl] : N;
                int s5 = (5 < cr) ? idxs[r][5][nl] : N;
                int s6 = (6 < cr) ? idxs[r][6][nl] : N;
                int s7 = (7 < cr) ? idxs[r][7][nl] : N;
                uint2 u0 = GLD8(s0), u1 = GLD8(s1), u2 = GLD8(s2), u3 = GLD8(s3);
                uint2 u4 = GLD8(s4), u5 = GLD8(s5), u6 = GLD8(s6), u7 = GLD8(s7);
                ACCF8(u0); ACCF8(u1); ACCF8(u2); ACCF8(u3);
                ACCF8(u4); ACCF8(u5); ACCF8(u6); ACCF8(u7);
            }
            if (cr > 8) {   // ~7% of threads
                int s0 = (8 < cr) ? idxs[r][8][nl] : N;
                int s1 = (9 < cr) ? idxs[r][9][nl] : N;
                int s2 = (10 < cr) ? idxs[r][10][nl] : N;
                int s3 = (11 < cr) ? idxs[r][11][nl] : N;
                int s4 = (12 < cr) ? idxs[r][12][nl] : N;
                int s5 = (13 < cr) ? idxs[r][13][nl] : N;
                int s6 = (14 < cr) ? idxs[r][14][nl] : N;
                int s7 = (15 < cr) ? idxs[r][15][nl] : N;
                uint2 u0 = GLD8(s0), u1 = GLD8(s1), u2 = GLD8(s2), u3 = GLD8(s3);
                uint2 u4 = GLD8(s4), u5 = GLD8(s5), u6 = GLD8(s6), u7 = GLD8(s7);
                ACCF8(u0); ACCF8(u1); ACCF8(u2); ACCF8(u3);
                ACCF8(u4); ACCF8(u5); ACCF8(u6); ACCF8(u7);
                if (cr > 16) {  // super rare: finish via chain walk
                    int e = ovfs[r][nl];
                    while (e >= 0) {
                        int2 ce = chain[e];
                        uint2 uu = GLD8(ce.x);
                        ACCF8(uu);
                        e = ce.y;
                    }
                }
            }
            float sc = 1.0f / (3.0f * fmaxf((float)cr, 1.0f));
            uint4 o;
            o.x = f2bf(a0 * sc) | (f2bf(a1 * sc) << 16);
            o.y = f2bf(a2 * sc) | (f2bf(a3 * sc) << 16);
            o.z = f2bf(a4 * sc) | (f2bf(a5 * sc) << 16);
            o.w = f2bf(a6 * sc) | (f2bf(a7 * sc) << 16);
            Ald[((rg * 6 + r * 2 + kgl) << 6) + lane] = o;
        }
        __syncthreads();

        // ---- MFMA this half: 6 kg (3 rel x 2 k-blocks) ----
#pragma unroll
        for (int r = 0; r < NR; ++r)
#pragma unroll
            for (int kb = 0; kb < 2; ++kb) {
                int kgA = r * 2 + kb;                   // Ald kg index
                int kgB = r * 4 + khalf * 2 + kb;       // Wb kg index
                short8 a[2], b[2];
#pragma unroll
                for (int m = 0; m < 2; ++m)
                    a[m] = Ap[(((wr * 2 + m) * 6 + kgA) << 6) + lane];
#pragma unroll
                for (int n = 0; n < 2; ++n)
                    b[n] = Bp[(((size_t)kgB * 8) + wc * 2 + n) * 64 + lane];
#pragma unroll
                for (int m = 0; m < 2; ++m)
#pragma unroll
                    for (int n = 0; n < 2; ++n)
                        acc[m][n] = __builtin_amdgcn_mfma_f32_16x16x32_bf16(
                            a[m], b[n], acc[m][n], 0, 0, 0);
            }
        __syncthreads();
    }
#undef ACCF8
#undef GLD8

    // epilogue: out = bf2f(hb) + acc. D layout: col=lane&15, row=(lane>>4)*4+reg
    int col0 = wc * 32 + (lane & 15);
    int rloc = wr * 32 + ((lane >> 4) << 2);
#pragma unroll
    for (int m = 0; m < 2; ++m)
#pragma unroll
        for (int rr = 0; rr < 4; ++rr) {
            int row = blk * TN + rloc + m * 16 + rr;
            if (row < N) {
                const unsigned short* ap = hb + ((size_t)row << 7) + col0;
                float* op = out + ((size_t)row << 7) + col0;
#pragma unroll
                for (int n = 0; n < 2; ++n)
                    op[n * 16] =
                        __uint_as_float((unsigned int)ap[n * 16] << 16) +
                        acc[m][n][rr];
            }
        }
}

extern "C" void kernel_launch(void* const* d_in, const int* in_sizes, int n_in,
                              void* d_out, int out_size, void* d_ws, size_t ws_size,
                              hipStream_t stream) {
    const float* h = (const float*)d_in[0];
    const float* W = (const float*)d_in[1];
    const int* src = (const int*)d_in[2];
    const int* dst = (const int*)d_in[3];
    float* out = (float*)d_out;

    const int N = in_sizes[0] / D;     // 100000
    const int E = in_sizes[2] / NR;    // 500000
    const int RN = NR * N;
    const int nbE = (E + 255) / 256;

    auto al16 = [](size_t x) { return (x + 15) & ~(size_t)15; };
    size_t sz_hb = al16((size_t)(N + 1) * D * 2);   // bf16 + zero row
    size_t sz_h8 = al16((size_t)(N + 1) * D);       // fp8 + zero row
    size_t sz_Wb = al16((size_t)12 * 8 * 64 * 8 * 2);
    size_t sz_head = al16((size_t)RN * 4);

    char* p = (char*)d_ws;
    unsigned short* hb = (unsigned short*)p; p += sz_hb;
    unsigned char*  h8 = (unsigned char*)p;  p += sz_h8;
    unsigned short* Wb = (unsigned short*)p; p += sz_Wb;
    int*  head  = (int*)p;  p += sz_head;
    int2* chain = (int2*)p;

    hipMemsetAsync(head, 0xFF, (size_t)RN * 4, stream);   // head = -1
    int n8 = N * D / 8, n8tot = (N + 1) * D / 8;
    int nbConv = (n8tot + 255) / 256;
    prep_k<<<nbConv + 24, 256, 0, stream>>>(h, hb, h8, W, Wb, n8, n8tot, nbConv);
    chain_k<<<NR * nbE, 256, 0, stream>>>(src, dst, head, chain, E, N, nbE);

    int nb = (N + TN - 1) / TN;
    fused_k<<<nb, 512, 0, stream>>>(h8, hb, head, chain, Wb, out, N);
}

// Round 13
// 201.640 us; speedup vs baseline: 1.1712x; 1.1712x over previous
//
#include <hip/hip_runtime.h>

#define D 128
#define TN 64      // nodes per block
#define NR 3       // relations
#define PAD 16     // csr slots per (rel,node)

typedef short short8 __attribute__((ext_vector_type(8)));
typedef float f32x4 __attribute__((ext_vector_type(4)));
typedef float f32x2 __attribute__((ext_vector_type(2)));

// round-to-nearest-even f32 -> bf16 bits
__device__ __forceinline__ unsigned int f2bf(float x) {
    unsigned int u = __float_as_uint(x);
    return (u + 0x7fffu + ((u >> 16) & 1u)) >> 16;
}

// ---------------- prep + chain (merged): block-range dispatch ----------------
// [0,nbConv): h -> {bf16 hb, fp8 h8} (+zero sink rows)
// [nbConv, nbConv+24): W pack to B-fragment order [12][8][64][8] bf16
// [nbConv+24, ...): chain build (one pass, coalesced 8B writes)
__global__ __launch_bounds__(256) void prep_chain_k(
    const float* __restrict__ h, unsigned short* __restrict__ hb,
    unsigned char* __restrict__ h8, const float* __restrict__ W,
    unsigned short* __restrict__ Wb, const int* __restrict__ src,
    const int* __restrict__ dst, int* __restrict__ head,
    int2* __restrict__ chain, int n8, int n8tot, int nbConv, int E, int N,
    int nbE) {
    int bid = blockIdx.x;
    if (bid < nbConv) {
        int i = bid * 256 + threadIdx.x;
        if (i >= n8tot) return;
        if (i >= n8) {  // zero sink row
            ((uint4*)hb)[i] = make_uint4(0u, 0u, 0u, 0u);
            ((uint2*)h8)[i] = make_uint2(0u, 0u);
            return;
        }
        const float4* hp = (const float4*)h;
        float4 v0 = hp[2 * i + 0], v1 = hp[2 * i + 1];
        uint4 o;
        o.x = f2bf(v0.x) | (f2bf(v0.y) << 16);
        o.y = f2bf(v0.z) | (f2bf(v0.w) << 16);
        o.z = f2bf(v1.x) | (f2bf(v1.y) << 16);
        o.w = f2bf(v1.z) | (f2bf(v1.w) << 16);
        ((uint4*)hb)[i] = o;
        int w0 = __builtin_amdgcn_cvt_pk_fp8_f32(v0.x, v0.y, 0, false);
        w0 = __builtin_amdgcn_cvt_pk_fp8_f32(v0.z, v0.w, w0, true);
        int w1 = __builtin_amdgcn_cvt_pk_fp8_f32(v1.x, v1.y, 0, false);
        w1 = __builtin_amdgcn_cvt_pk_fp8_f32(v1.z, v1.w, w1, true);
        ((uint2*)h8)[i] = make_uint2((unsigned)w0, (unsigned)w1);
        return;
    }
    bid -= nbConv;
    if (bid < 24) {
        int t = bid * 256 + threadIdx.x;
        if (t >= 12 * 8 * 64) return;
        int lane = t & 63, cg = (t >> 6) & 7, kg = t >> 9;
        int col = cg * 16 + (lane & 15);
        int r = kg >> 2;
        int klocal = (kg & 3) * 32 + (lane >> 4) * 8;
        const float* Ws = W + ((size_t)r * D + klocal) * D + col;
        uint4 o;
        o.x = f2bf(Ws[0 * D]) | (f2bf(Ws[1 * D]) << 16);
        o.y = f2bf(Ws[2 * D]) | (f2bf(Ws[3 * D]) << 16);
        o.z = f2bf(Ws[4 * D]) | (f2bf(Ws[5 * D]) << 16);
        o.w = f2bf(Ws[6 * D]) | (f2bf(Ws[7 * D]) << 16);
        ((uint4*)Wb)[t] = o;
        return;
    }
    bid -= 24;
    int r = bid / nbE;
    int i = (bid - r * nbE) * 256 + threadIdx.x;
    if (i >= E) return;
    size_t gi = (size_t)r * E + i;
    int d = dst[gi];
    int s = src[gi];
    int old = atomicExch(&head[r * N + d], (int)gi);
    chain[gi] = make_int2(s, old);
}

// ---------------- flatten: chain -> padded CSR (one thread per (r,node)) -----
__global__ void flat_k(const int* __restrict__ head,
                       const int2* __restrict__ chain, int* __restrict__ csr,
                       int* __restrict__ deg, int* __restrict__ ovfp, int RN) {
    int rn = blockIdx.x * 256 + threadIdx.x;
    if (rn >= RN) return;
    int e = head[rn];
    int d = 0, ov = -1;
    int* cp = csr + ((size_t)rn << 4);
    while (e >= 0) {
        if (d == PAD) ov = e;
        int2 ce = chain[e];
        if (d < PAD) cp[d] = ce.x;
        ++d;
        e = ce.y;
    }
    deg[rn] = d;
    ovfp[rn] = ov;
}

// ---------------- fused: stage CSR -> 3x(fp8 gather rel -> MFMA rel) ---------
// Block = 512 threads, 64 output rows, K = 384 (3 rel x 128 feat).
// Gather: thread (nl = tid>>3, fb = tid&7) owns features [fb*16, fb*16+16);
// an edge's whole 128B fp8 row is read ONCE, coalesced (8 lanes x 16B).
// Decode via v_cvt_pk_f32_fp8 (1 inst / 2 elements).
// LDS: Ald 16 KB (one rel) + ilist 12 KB + degs 0.75 KB = ~29 KB.
__global__ __launch_bounds__(512) void fused_k(
    const unsigned char* __restrict__ h8, const unsigned short* __restrict__ hb,
    const int* __restrict__ csr, const int* __restrict__ deg,
    const int* __restrict__ ovfp, const int2* __restrict__ chain,
    const unsigned short* __restrict__ Wb, float* __restrict__ out, int N) {
    __shared__ uint4 Ald[4 * 4 * 64];       // 16 KB
    __shared__ int ilist[NR][PAD][TN];      // 12 KB
    __shared__ int degs_s[NR][TN];

    const int tid = threadIdx.x;
    const int blk = blockIdx.x;

    // ---- stage csr + deg into LDS (coalesced int4 reads) ----
    for (int i = tid; i < NR * TN * (PAD / 4); i += 512) {
        int jv = i & 3;
        int nl = (i >> 2) & (TN - 1);
        int r = i >> 8;
        int n = blk * TN + nl;
        if (n >= N) n = N - 1;
        int4 v = ((const int4*)(csr + ((size_t)(r * N + n) << 4)))[jv];
        ilist[r][jv * 4 + 0][nl] = v.x;
        ilist[r][jv * 4 + 1][nl] = v.y;
        ilist[r][jv * 4 + 2][nl] = v.z;
        ilist[r][jv * 4 + 3][nl] = v.w;
    }
    if (tid < NR * TN) {
        int r = tid / TN, nl = tid - r * TN;
        int n = blk * TN + nl;
        if (n >= N) n = N - 1;
        degs_s[r][nl] = deg[r * N + n];
    }
    __syncthreads();

    const int lane = tid & 63;
    const int nl = tid >> 3;                    // gather node 0..63
    const int fb = tid & 7;                     // gather feature block
    const int w = tid >> 6;                     // wave 0..7
    const int wr = w >> 2, wc = w & 3;          // 2 x 4 wave grid for MFMA
    int n_node = blk * TN + nl;
    if (n_node >= N) n_node = N - 1;

    const short8* Ap = (const short8*)Ald;
    const short8* Bp = (const short8*)Wb;
    f32x4 acc[2][2];
#pragma unroll
    for (int m = 0; m < 2; ++m)
#pragma unroll
        for (int n = 0; n < 2; ++n) acc[m][n] = (f32x4){0.f, 0.f, 0.f, 0.f};

#define CVT(x, hi) __builtin_amdgcn_cvt_pk_f32_fp8((int)(x), hi)
#define ACC16(u)                                                             \
    {                                                                        \
        f32x2 p;                                                             \
        p = CVT((u).x, false); a0 += p.x;  a1 += p.y;                        \
        p = CVT((u).x, true);  a2 += p.x;  a3 += p.y;                        \
        p = CVT((u).y, false); a4 += p.x;  a5 += p.y;                        \
        p = CVT((u).y, true);  a6 += p.x;  a7 += p.y;                        \
        p = CVT((u).z, false); a8 += p.x;  a9 += p.y;                        \
        p = CVT((u).z, true);  a10 += p.x; a11 += p.y;                       \
        p = CVT((u).w, false); a12 += p.x; a13 += p.y;                       \
        p = CVT((u).w, true);  a14 += p.x; a15 += p.y;                       \
    }
#define GLD(s) (*(const uint4*)(h8 + ((size_t)(s) << 7) + fb * 16))

    for (int r = 0; r < NR; ++r) {
        // ---- gather-mean rel r (full fp8 rows, single touch) ----
        int cr = degs_s[r][nl];
        float a0 = 0, a1 = 0, a2 = 0, a3 = 0, a4 = 0, a5 = 0, a6 = 0, a7 = 0,
              a8 = 0, a9 = 0, a10 = 0, a11 = 0, a12 = 0, a13 = 0, a14 = 0,
              a15 = 0;
        {   // first 8 edges, branchless sink-padded (8 x 16B in flight)
            int s0 = (0 < cr) ? ilist[r][0][nl] : N;
            int s1 = (1 < cr) ? ilist[r][1][nl] : N;
            int s2 = (2 < cr) ? ilist[r][2][nl] : N;
            int s3 = (3 < cr) ? ilist[r][3][nl] : N;
            int s4 = (4 < cr) ? ilist[r][4][nl] : N;
            int s5 = (5 < cr) ? ilist[r][5][nl] : N;
            int s6 = (6 < cr) ? ilist[r][6][nl] : N;
            int s7 = (7 < cr) ? ilist[r][7][nl] : N;
            uint4 u0 = GLD(s0), u1 = GLD(s1), u2 = GLD(s2), u3 = GLD(s3);
            uint4 u4 = GLD(s4), u5 = GLD(s5), u6 = GLD(s6), u7 = GLD(s7);
            ACC16(u0); ACC16(u1); ACC16(u2); ACC16(u3);
            ACC16(u4); ACC16(u5); ACC16(u6); ACC16(u7);
        }
        if (cr > 8) {   // ~7% of threads
            int s0 = (8 < cr) ? ilist[r][8][nl] : N;
            int s1 = (9 < cr) ? ilist[r][9][nl] : N;
            int s2 = (10 < cr) ? ilist[r][10][nl] : N;
            int s3 = (11 < cr) ? ilist[r][11][nl] : N;
            int s4 = (12 < cr) ? ilist[r][12][nl] : N;
            int s5 = (13 < cr) ? ilist[r][13][nl] : N;
            int s6 = (14 < cr) ? ilist[r][14][nl] : N;
            int s7 = (15 < cr) ? ilist[r][15][nl] : N;
            uint4 u0 = GLD(s0), u1 = GLD(s1), u2 = GLD(s2), u3 = GLD(s3);
            uint4 u4 = GLD(s4), u5 = GLD(s5), u6 = GLD(s6), u7 = GLD(s7);
            ACC16(u0); ACC16(u1); ACC16(u2); ACC16(u3);
            ACC16(u4); ACC16(u5); ACC16(u6); ACC16(u7);
            if (cr > PAD) {  // super rare: finish via chain walk
                int e = ovfp[r * N + n_node];
                while (e >= 0) {
                    int2 ce = chain[e];
                    uint4 uu = GLD(ce.x);
                    ACC16(uu);
                    e = ce.y;
                }
            }
        }
        float sc = 1.0f / (3.0f * fmaxf((float)cr, 1.0f));
        // write 16 bf16 to Ald: rg=nl>>4, kg=fb>>1, jgroups (fb&1)*2 + {0,1}
        int abase = (((nl >> 4) << 2) + (fb >> 1)) * 64 + (nl & 15);
        uint4 o;
        o.x = f2bf(a0 * sc) | (f2bf(a1 * sc) << 16);
        o.y = f2bf(a2 * sc) | (f2bf(a3 * sc) << 16);
        o.z = f2bf(a4 * sc) | (f2bf(a5 * sc) << 16);
        o.w = f2bf(a6 * sc) | (f2bf(a7 * sc) << 16);
        Ald[abase + ((fb & 1) * 2 + 0) * 16] = o;
        o.x = f2bf(a8 * sc) | (f2bf(a9 * sc) << 16);
        o.y = f2bf(a10 * sc) | (f2bf(a11 * sc) << 16);
        o.z = f2bf(a12 * sc) | (f2bf(a13 * sc) << 16);
        o.w = f2bf(a14 * sc) | (f2bf(a15 * sc) << 16);
        Ald[abase + ((fb & 1) * 2 + 1) * 16] = o;
        __syncthreads();

        // ---- MFMA rel r: 4 kg ----
#pragma unroll
        for (int kg = 0; kg < 4; ++kg) {
            short8 a[2], b[2];
#pragma unroll
            for (int m = 0; m < 2; ++m)
                a[m] = Ap[(((wr * 2 + m) << 2) + kg) * 64 + lane];
#pragma unroll
            for (int n = 0; n < 2; ++n)
                b[n] = Bp[(((size_t)(r * 4 + kg) * 8) + wc * 2 + n) * 64 + lane];
#pragma unroll
            for (int m = 0; m < 2; ++m)
#pragma unroll
                for (int n = 0; n < 2; ++n)
                    acc[m][n] = __builtin_amdgcn_mfma_f32_16x16x32_bf16(
                        a[m], b[n], acc[m][n], 0, 0, 0);
        }
        __syncthreads();
    }
#undef CVT
#undef ACC16
#undef GLD

    // epilogue: out = bf2f(hb) + acc. D layout: col=lane&15, row=(lane>>4)*4+reg
    int col0 = wc * 32 + (lane & 15);
    int rloc = wr * 32 + ((lane >> 4) << 2);
#pragma unroll
    for (int m = 0; m < 2; ++m)
#pragma unroll
        for (int rr = 0; rr < 4; ++rr) {
            int row = blk * TN + rloc + m * 16 + rr;
            if (row < N) {
                const unsigned short* ap = hb + ((size_t)row << 7) + col0;
                float* op = out + ((size_t)row << 7) + col0;
#pragma unroll
                for (int n = 0; n < 2; ++n)
                    op[n * 16] =
                        __uint_as_float((unsigned int)ap[n * 16] << 16) +
                        acc[m][n][rr];
            }
        }
}

extern "C" void kernel_launch(void* const* d_in, const int* in_sizes, int n_in,
                              void* d_out, int out_size, void* d_ws, size_t ws_size,
                              hipStream_t stream) {
    const float* h = (const float*)d_in[0];
    const float* W = (const float*)d_in[1];
    const int* src = (const int*)d_in[2];
    const int* dst = (const int*)d_in[3];
    float* out = (float*)d_out;

    const int N = in_sizes[0] / D;     // 100000
    const int E = in_sizes[2] / NR;    // 500000
    const int RN = NR * N;
    const int nbE = (E + 255) / 256;

    auto al16 = [](size_t x) { return (x + 15) & ~(size_t)15; };
    size_t sz_hb = al16((size_t)(N + 1) * D * 2);   // bf16 + zero row
    size_t sz_h8 = al16((size_t)(N + 1) * D);       // fp8 + zero row
    size_t sz_Wb = al16((size_t)12 * 8 * 64 * 8 * 2);
    size_t sz_head = al16((size_t)RN * 4);
    size_t sz_chain = al16((size_t)NR * E * 8);
    size_t sz_csr = al16((size_t)RN * PAD * 4);
    size_t sz_deg = al16((size_t)RN * 4);

    char* p = (char*)d_ws;
    unsigned short* hb = (unsigned short*)p; p += sz_hb;
    unsigned char*  h8 = (unsigned char*)p;  p += sz_h8;
    unsigned short* Wb = (unsigned short*)p; p += sz_Wb;
    int*  head  = (int*)p;  p += sz_head;
    int2* chain = (int2*)p; p += sz_chain;
    int*  csr   = (int*)p;  p += sz_csr;
    int*  deg   = (int*)p;  p += sz_deg;
    int*  ovfp  = (int*)p;

    hipMemsetAsync(head, 0xFF, (size_t)RN * 4, stream);   // head = -1
    int n8 = N * D / 8, n8tot = (N + 1) * D / 8;
    int nbConv = (n8tot + 255) / 256;
    prep_chain_k<<<nbConv + 24 + NR * nbE, 256, 0, stream>>>(
        h, hb, h8, W, Wb, src, dst, head, chain, n8, n8tot, nbConv, E, N, nbE);
    flat_k<<<(RN + 255) / 256, 256, 0, stream>>>(head, chain, csr, deg, ovfp, RN);

    int nb = (N + TN - 1) / TN;
    fused_k<<<nb, 512, 0, stream>>>(h8, hb, csr, deg, ovfp, chain, Wb, out, N);
}